// Round 1
// baseline (380.549 us; speedup 1.0000x reference)
//
#include <hip/hip_runtime.h>

// ---------------------------------------------------------------------------
// SOABlock: f,g = BN(ReLU(1x1conv)), h = 1x1conv, attn = softmax(f^T g /16),
// z = attn @ h^T, out = v(z) + x.   B=16, C=512, MID=256, N=48*48=2304.
// ---------------------------------------------------------------------------

#define B_    16
#define C_    512
#define MID_  256
#define N_    2304
#define NT_   (B_ * N_)          // 36864

typedef unsigned short u16;
typedef unsigned long long ull;
typedef short s16x8 __attribute__((ext_vector_type(8)));   // 8 bf16 (4 VGPR)
typedef float f32x4 __attribute__((ext_vector_type(4)));

// exp constants: P = exp(S/16 - 20) = exp2(S*K1F - K2F)
#define K1F 0.09016844005556021f
#define K2F 28.853900817779268f

__device__ __forceinline__ u16 f2bf(float f) {
  unsigned int u = __float_as_uint(f);
  return (u16)((u + 0x7FFFu + ((u >> 16) & 1u)) >> 16);
}
__device__ __forceinline__ ull pack4bf(float a, float b, float c, float d) {
  return (ull)f2bf(a) | ((ull)f2bf(b) << 16) | ((ull)f2bf(c) << 32) | ((ull)f2bf(d) << 48);
}

#define GLL16(src, dst)                                                        \
  __builtin_amdgcn_global_load_lds(                                            \
      (const __attribute__((address_space(1))) void*)(src),                    \
      (__attribute__((address_space(3))) void*)(dst), 16, 0, 0)

// ---------------------------------------------------------------------------
// ws layout (bytes)
#define OFF_XT   0ull            // xT bf16 [36864][512]  (37,748,736 B); z aliases here later
#define OFF_FG   37748736ull     // fg bf16 [36864][512]  (f at o<256, g at 256..511)
#define OFF_HT   75497472ull     // hT bf16 [16][256][2304]
#define OFF_WB   94371840ull     // Wfgh bf16 [768][512]
#define OFF_VW   95158272ull     // v_w bf16 [512][256]
#define OFF_BIAS 95420416ull     // bias f32 [768]

// ---------------------------------------------------------------------------
// K0: fold BN into conv weights, convert weights to bf16.
__global__ __launch_bounds__(64) void k_prep(
    const float* __restrict__ f_w, const float* __restrict__ f_b2, const float* __restrict__ f_gamma,
    const float* __restrict__ f_beta, const float* __restrict__ f_mean, const float* __restrict__ f_var,
    const float* __restrict__ g_w, const float* __restrict__ g_b2, const float* __restrict__ g_gamma,
    const float* __restrict__ g_beta, const float* __restrict__ g_mean, const float* __restrict__ g_var,
    const float* __restrict__ h_w, const float* __restrict__ h_b2, const float* __restrict__ v_w,
    u16* __restrict__ Wb, u16* __restrict__ vwb, float* __restrict__ biasb)
{
  const int bid = blockIdx.x, t = threadIdx.x;
  if (bid < 768) {
    const int o = bid;
    const float* wsrc;
    float scale, bias_v;
    if (o < 256) {
      scale = f_gamma[o] * rsqrtf(f_var[o] + 1e-5f);
      wsrc = f_w + o * 512;
      bias_v = (f_b2[o] - f_mean[o]) * scale + f_beta[o];
    } else if (o < 512) {
      const int i = o - 256;
      scale = g_gamma[i] * rsqrtf(g_var[i] + 1e-5f);
      wsrc = g_w + i * 512;
      bias_v = (g_b2[i] - g_mean[i]) * scale + g_beta[i];
    } else {
      const int i = o - 512;
      scale = 1.0f;
      wsrc = h_w + i * 512;
      bias_v = h_b2[i];
    }
#pragma unroll
    for (int j = 0; j < 8; ++j)
      Wb[o * 512 + t * 8 + j] = f2bf(wsrc[t * 8 + j] * scale);
    if (t == 0) biasb[o] = bias_v;
  } else {
    const int r = bid - 768;
#pragma unroll
    for (int j = 0; j < 4; ++j)
      vwb[r * 256 + t * 4 + j] = f2bf(v_w[r * 256 + t * 4 + j]);
  }
}

// ---------------------------------------------------------------------------
// K1: x [b][c][n] f32  ->  xT [b*n][c] bf16   (64x64 tiles via LDS)
__global__ __launch_bounds__(256) void k_trx(const float* __restrict__ x, u16* __restrict__ xT)
{
  __shared__ __align__(16) u16 T[64 * 72];
  const int t = threadIdx.x;
  const int n0 = blockIdx.x * 64, c0 = blockIdx.y * 64, b = blockIdx.z;
#pragma unroll
  for (int it = 0; it < 4; ++it) {
    const int cr = it * 16 + (t >> 4);
    const int nc = (t & 15) * 4;
    const float4 v = *(const float4*)(x + ((size_t)(b * 512 + c0 + cr)) * N_ + n0 + nc);
    T[cr * 72 + nc + 0] = f2bf(v.x);
    T[cr * 72 + nc + 1] = f2bf(v.y);
    T[cr * 72 + nc + 2] = f2bf(v.z);
    T[cr * 72 + nc + 3] = f2bf(v.w);
  }
  __syncthreads();
#pragma unroll
  for (int it = 0; it < 2; ++it) {
    const int nr = it * 32 + (t >> 3);
    const int ch = t & 7;
    s16x8 val;
#pragma unroll
    for (int j = 0; j < 8; ++j) val[j] = (short)T[(ch * 8 + j) * 72 + nr];
    *(s16x8*)(xT + ((size_t)(b * N_ + n0 + nr)) * 512 + c0 + ch * 8) = val;
  }
}

// ---------------------------------------------------------------------------
// K2: GEMM1  D[o][n] = Wfgh[o][c] * x[c][n]  (+bias, relu for o<512)
//   o<512 -> fg[n][o] (8B packed stores), o>=512 -> hT[b][o-512][n] (scalar)
//   128x128 tile, BK=64, 4 waves, global_load_lds w/ source-side XOR swizzle.
__global__ __launch_bounds__(256) void k_gemm1(const u16* __restrict__ Wb, const u16* __restrict__ xT,
                                               const float* __restrict__ biasb,
                                               u16* __restrict__ fg, u16* __restrict__ hT)
{
  __shared__ __align__(16) u16 Al[128 * 64];
  __shared__ __align__(16) u16 Bl[128 * 64];
  const int tid = threadIdx.x, lane = tid & 63, w = tid >> 6;
  const int wr = w >> 1, wc = w & 1;
  const int row16 = lane & 15, g = lane >> 4;
  const int nt = blockIdx.x, mt = blockIdx.y;
  const int nbase = nt * 128;
  const int sr = lane >> 3, sj = lane & 7;

  f32x4 acc[4][4] = {};

  for (int kt = 0; kt < 8; ++kt) {
#pragma unroll
    for (int s = 0; s < 4; ++s) {
      const int r = s * 32 + w * 8 + sr;
      const u16* src = Wb + (size_t)(mt * 128 + r) * 512 + kt * 64 + ((sj ^ (r & 7)) * 8);
      GLL16(src, Al + (s * 32 + w * 8) * 64);
    }
#pragma unroll
    for (int s = 0; s < 4; ++s) {
      const int r = s * 32 + w * 8 + sr;
      const u16* src = xT + (size_t)(nbase + r) * 512 + kt * 64 + ((sj ^ (r & 7)) * 8);
      GLL16(src, Bl + (s * 32 + w * 8) * 64);
    }
    __syncthreads();
#pragma unroll
    for (int kk = 0; kk < 2; ++kk) {
      s16x8 a[4], b[4];
#pragma unroll
      for (int m = 0; m < 4; ++m) {
        const int row = wr * 64 + m * 16 + row16;
        const int ch = (kk * 4 + g) ^ (row & 7);
        a[m] = *(const s16x8*)(Al + row * 64 + ch * 8);
      }
#pragma unroll
      for (int n = 0; n < 4; ++n) {
        const int row = wc * 64 + n * 16 + row16;
        const int ch = (kk * 4 + g) ^ (row & 7);
        b[n] = *(const s16x8*)(Bl + row * 64 + ch * 8);
      }
#pragma unroll
      for (int m = 0; m < 4; ++m)
#pragma unroll
        for (int n = 0; n < 4; ++n)
          acc[m][n] = __builtin_amdgcn_mfma_f32_16x16x32_bf16(a[m], b[n], acc[m][n], 0, 0, 0);
    }
    __syncthreads();
  }

  const int bt = nbase / N_;          // batch (uniform per block)
  if (mt < 4) {                        // f/g region: relu, packed 8B stores to fg[n][o]
#pragma unroll
    for (int m = 0; m < 4; ++m) {
      const int o0 = mt * 128 + wr * 64 + m * 16 + g * 4;
      const float b0 = biasb[o0], b1 = biasb[o0 + 1], b2 = biasb[o0 + 2], b3 = biasb[o0 + 3];
#pragma unroll
      for (int n = 0; n < 4; ++n) {
        const int nn = nbase + wc * 64 + n * 16 + row16;
        const f32x4 v = acc[m][n];
        *(ull*)(fg + (size_t)nn * 512 + o0) =
            pack4bf(fmaxf(v[0] + b0, 0.f), fmaxf(v[1] + b1, 0.f),
                    fmaxf(v[2] + b2, 0.f), fmaxf(v[3] + b3, 0.f));
      }
    }
  } else {                             // h region: scalar stores to hT[b][c][n]
#pragma unroll
    for (int m = 0; m < 4; ++m) {
      const int o0 = mt * 128 + wr * 64 + m * 16 + g * 4;   // 512..767
#pragma unroll
      for (int n = 0; n < 4; ++n) {
        const int nn = nbase + wc * 64 + n * 16 + row16;
        const int nl = nn - bt * N_;
#pragma unroll
        for (int i = 0; i < 4; ++i)
          hT[(size_t)(bt * 256 + (o0 - 512) + i) * N_ + nl] = f2bf(acc[m][n][i] + biasb[o0 + i]);
      }
    }
  }
}

// ---------------------------------------------------------------------------
// K3: flash attention (no-max softmax: P = exp(S/16 - 20), divide by rowsum).
//   Q = fg[.][0:256], K = fg[.][256:512], V = hT.   64 q-rows/block, 4 waves,
//   KV tile = 32.  PV computed as V^T * P^T -> z[b*n][c] bf16.
__global__ __launch_bounds__(256) void k_flash(const u16* __restrict__ fg, const u16* __restrict__ hT,
                                               u16* __restrict__ z)
{
  __shared__ __align__(16) u16 Kl[32 * 256];   // [m][c], 16B-chunk XOR swizzled
  __shared__ __align__(16) u16 Vl[128 * 64];   // [c>>1][(c&1)*32 + m] chunk-swizzled
  __shared__ __align__(16) u16 Pl[4][512];     // per-wave [16 n][32 m] swizzled
  const int tid = threadIdx.x, lane = tid & 63, w = tid >> 6;
  const int row16 = lane & 15, g = lane >> 4;
  const int b = blockIdx.y, nblk = blockIdx.x;
  const int qrow = nblk * 64 + w * 16 + row16;

  const u16* qbase = fg + (size_t)(b * N_ + qrow) * 512;
  s16x8 q[8];
#pragma unroll
  for (int kt = 0; kt < 8; ++kt) q[kt] = *(const s16x8*)(qbase + kt * 32 + g * 8);

  f32x4 accz[16] = {};
  float denom[4] = {0.f, 0.f, 0.f, 0.f};
  u16* Pw = Pl[w];
  const int kr = lane >> 5, kj = lane & 31;
  const int vr = lane >> 3, vj = lane & 7;

  for (int it = 0; it < 72; ++it) {
    const int m0 = it * 32;
#pragma unroll
    for (int s = 0; s < 4; ++s) {           // stage K: 32 rows x 512B
      const int r = s * 8 + w * 2 + kr;
      const u16* src = fg + (size_t)(b * N_ + m0 + r) * 512 + 256 + ((kj ^ (r & 7)) * 8);
      GLL16(src, Kl + (s * 8 + w * 2) * 256);
    }
#pragma unroll
    for (int s = 0; s < 4; ++s) {           // stage V^T: 128 rows x 128B
      const int r2 = s * 32 + w * 8 + vr;
      const int jg = vj ^ (r2 & 7);
      const int c = r2 * 2 + (jg >> 2);
      const u16* src = hT + (size_t)(b * 256 + c) * N_ + m0 + (jg & 3) * 8;
      GLL16(src, Vl + (s * 32 + w * 8) * 64);
    }
    __syncthreads();

    // S = Q K^T  (two 16x16 m-tiles)
    f32x4 s0 = {}, s1 = {};
#pragma unroll
    for (int kt = 0; kt < 8; ++kt) {
      const int ch0 = (kt * 4 + g) ^ (row16 & 7);
      const s16x8 kf0 = *(const s16x8*)(Kl + row16 * 256 + ch0 * 8);
      s0 = __builtin_amdgcn_mfma_f32_16x16x32_bf16(q[kt], kf0, s0, 0, 0, 0);
      const int r1 = 16 + row16;
      const int ch1 = (kt * 4 + g) ^ (r1 & 7);
      const s16x8 kf1 = *(const s16x8*)(Kl + r1 * 256 + ch1 * 8);
      s1 = __builtin_amdgcn_mfma_f32_16x16x32_bf16(q[kt], kf1, s1, 0, 0, 0);
    }

    // exp, write P to per-wave LDS, accumulate row sums
    float ts[4];
#pragma unroll
    for (int i = 0; i < 4; ++i) {
      const float p0 = exp2f(s0[i] * K1F - K2F);
      const float p1 = exp2f(s1[i] * K1F - K2F);
      ts[i] = p0 + p1;
      const int nr = g * 4 + i;
      const int slot0 = (row16 >> 3) ^ (nr & 3);
      Pw[nr * 32 + slot0 * 8 + (row16 & 7)] = f2bf(p0);
      const int slot1 = (2 + (row16 >> 3)) ^ (nr & 3);
      Pw[nr * 32 + slot1 * 8 + (row16 & 7)] = f2bf(p1);
    }
#pragma unroll
    for (int i = 0; i < 4; ++i) {
      float t2 = ts[i];
      t2 += __shfl_xor(t2, 1);
      t2 += __shfl_xor(t2, 2);
      t2 += __shfl_xor(t2, 4);
      t2 += __shfl_xor(t2, 8);
      denom[i] += t2;
    }
    __syncthreads();   // safety: P writes (cross-lane) visible before frag reads

    // z^T accumulation: D[c][n] += V^T[c][m] * P^T[m][n]
    const s16x8 pb = *(const s16x8*)(Pw + row16 * 32 + ((g ^ (row16 & 3)) * 8));
#pragma unroll
    for (int ct = 0; ct < 16; ++ct) {
      const int c = ct * 16 + row16;
      const int r2 = c >> 1;
      const int slot = ((c & 1) * 4 + g) ^ (r2 & 7);
      const s16x8 vf = *(const s16x8*)(Vl + r2 * 64 + slot * 8);
      accz[ct] = __builtin_amdgcn_mfma_f32_16x16x32_bf16(vf, pb, accz[ct], 0, 0, 0);
    }
    __syncthreads();
  }

  // epilogue: divide by denom, store z[b*n][c]
  const int srcl = (row16 >> 2) << 4;
  const float dv0 = __shfl(denom[0], srcl);
  const float dv1 = __shfl(denom[1], srcl);
  const float dv2 = __shfl(denom[2], srcl);
  const float dv3 = __shfl(denom[3], srcl);
  const float dsel = (row16 & 2) ? ((row16 & 1) ? dv3 : dv2) : ((row16 & 1) ? dv1 : dv0);
  const float inv = 1.0f / dsel;
  u16* zr = z + (size_t)(b * N_ + qrow) * 256;
#pragma unroll
  for (int ct = 0; ct < 16; ++ct)
    *(ull*)(zr + ct * 16 + g * 4) =
        pack4bf(accz[ct][0] * inv, accz[ct][1] * inv, accz[ct][2] * inv, accz[ct][3] * inv);
}

// ---------------------------------------------------------------------------
// K4: GEMM2  out[b][o][n] = v_w[o][c] * z[c][n] + v_b[o] + x[b][o][n]
//   computed as D[n][o] = z[n][c] * v_w^T[c][o]; float4 stores along n.
__global__ __launch_bounds__(256) void k_gemm2(const u16* __restrict__ zb, const u16* __restrict__ vwb,
                                               const float* __restrict__ v_b, const float* __restrict__ x,
                                               float* __restrict__ out)
{
  __shared__ __align__(16) u16 Al[128 * 64];
  __shared__ __align__(16) u16 Bl[128 * 64];
  const int tid = threadIdx.x, lane = tid & 63, w = tid >> 6;
  const int wr = w >> 1, wc = w & 1;
  const int row16 = lane & 15, g = lane >> 4;
  const int nt = blockIdx.x, ot = blockIdx.y;
  const int nbase = nt * 128;
  const int sr = lane >> 3, sj = lane & 7;

  f32x4 acc[4][4] = {};

  for (int kt = 0; kt < 4; ++kt) {
#pragma unroll
    for (int s = 0; s < 4; ++s) {
      const int r = s * 32 + w * 8 + sr;
      const u16* src = zb + (size_t)(nbase + r) * 256 + kt * 64 + ((sj ^ (r & 7)) * 8);
      GLL16(src, Al + (s * 32 + w * 8) * 64);
    }
#pragma unroll
    for (int s = 0; s < 4; ++s) {
      const int r = s * 32 + w * 8 + sr;
      const u16* src = vwb + (size_t)(ot * 128 + r) * 256 + kt * 64 + ((sj ^ (r & 7)) * 8);
      GLL16(src, Bl + (s * 32 + w * 8) * 64);
    }
    __syncthreads();
#pragma unroll
    for (int kk = 0; kk < 2; ++kk) {
      s16x8 a[4], b[4];
#pragma unroll
      for (int m = 0; m < 4; ++m) {
        const int row = wr * 64 + m * 16 + row16;
        const int ch = (kk * 4 + g) ^ (row & 7);
        a[m] = *(const s16x8*)(Al + row * 64 + ch * 8);
      }
#pragma unroll
      for (int n = 0; n < 4; ++n) {
        const int row = wc * 64 + n * 16 + row16;
        const int ch = (kk * 4 + g) ^ (row & 7);
        b[n] = *(const s16x8*)(Bl + row * 64 + ch * 8);
      }
#pragma unroll
      for (int m = 0; m < 4; ++m)
#pragma unroll
        for (int n = 0; n < 4; ++n)
          acc[m][n] = __builtin_amdgcn_mfma_f32_16x16x32_bf16(a[m], b[n], acc[m][n], 0, 0, 0);
    }
    __syncthreads();
  }

  const int bt = nbase / N_;
#pragma unroll
  for (int m = 0; m < 4; ++m) {
    const int nl0 = (nbase - bt * N_) + wr * 64 + m * 16 + g * 4;
#pragma unroll
    for (int n = 0; n < 4; ++n) {
      const int o = ot * 128 + wc * 64 + n * 16 + row16;
      const float vb = v_b[o];
      const size_t off = (size_t)(bt * 512 + o) * N_ + nl0;
      const float4 xv = *(const float4*)(x + off);
      float4 r;
      r.x = acc[m][n][0] + vb + xv.x;
      r.y = acc[m][n][1] + vb + xv.y;
      r.z = acc[m][n][2] + vb + xv.z;
      r.w = acc[m][n][3] + vb + xv.w;
      *(float4*)(out + off) = r;
    }
  }
}

// ---------------------------------------------------------------------------
extern "C" void kernel_launch(void* const* d_in, const int* in_sizes, int n_in,
                              void* d_out, int out_size, void* d_ws, size_t ws_size,
                              hipStream_t stream)
{
  const float* x       = (const float*)d_in[0];
  const float* f_w     = (const float*)d_in[1];
  const float* f_b     = (const float*)d_in[2];
  const float* f_gamma = (const float*)d_in[3];
  const float* f_beta  = (const float*)d_in[4];
  const float* f_mean  = (const float*)d_in[5];
  const float* f_var   = (const float*)d_in[6];
  const float* g_w     = (const float*)d_in[7];
  const float* g_b     = (const float*)d_in[8];
  const float* g_gamma = (const float*)d_in[9];
  const float* g_beta  = (const float*)d_in[10];
  const float* g_mean  = (const float*)d_in[11];
  const float* g_var   = (const float*)d_in[12];
  const float* h_w     = (const float*)d_in[13];
  const float* h_b     = (const float*)d_in[14];
  const float* v_w     = (const float*)d_in[15];
  const float* v_b     = (const float*)d_in[16];

  char* ws = (char*)d_ws;
  u16*  xT    = (u16*)(ws + OFF_XT);
  u16*  fg    = (u16*)(ws + OFF_FG);
  u16*  hT    = (u16*)(ws + OFF_HT);
  u16*  Wb    = (u16*)(ws + OFF_WB);
  u16*  vwb   = (u16*)(ws + OFF_VW);
  float* biasb = (float*)(ws + OFF_BIAS);
  u16*  z     = (u16*)(ws + OFF_XT);   // reuses xT region (xT dead after GEMM1)
  float* out  = (float*)d_out;

  hipLaunchKernelGGL(k_prep, dim3(1280), dim3(64), 0, stream,
                     f_w, f_b, f_gamma, f_beta, f_mean, f_var,
                     g_w, g_b, g_gamma, g_beta, g_mean, g_var,
                     h_w, h_b, v_w, Wb, vwb, biasb);
  hipLaunchKernelGGL(k_trx, dim3(36, 8, 16), dim3(256), 0, stream, x, xT);
  hipLaunchKernelGGL(k_gemm1, dim3(288, 6), dim3(256), 0, stream, Wb, xT, biasb, fg, hT);
  hipLaunchKernelGGL(k_flash, dim3(36, 16), dim3(256), 0, stream, fg, hT, z);
  hipLaunchKernelGGL(k_gemm2, dim3(288, 4), dim3(256), 0, stream, z, vwb, v_b, x, out);
}

// Round 2
// 358.526 us; speedup vs baseline: 1.0614x; 1.0614x over previous
//
#include <hip/hip_runtime.h>

// ---------------------------------------------------------------------------
// SOABlock: f,g = BN(ReLU(1x1conv)), h = 1x1conv, attn = softmax(f^T g /16),
// z = attn @ h^T, out = v(z) + x.   B=16, C=512, MID=256, N=48*48=2304.
// ---------------------------------------------------------------------------

#define B_    16
#define C_    512
#define MID_  256
#define N_    2304
#define NT_   (B_ * N_)          // 36864

typedef unsigned short u16;
typedef unsigned int   u32;
typedef unsigned long long ull;
typedef short s16x8 __attribute__((ext_vector_type(8)));   // 8 bf16 (4 VGPR)
typedef float f32x4 __attribute__((ext_vector_type(4)));

// exp constants: P = exp(S/16 - 20) = exp2(S*K1F - K2F)
#define K1F 0.09016844005556021f
#define K2F 28.853900817779268f

#define MFMA16(a, b, c) __builtin_amdgcn_mfma_f32_16x16x32_bf16(a, b, c, 0, 0, 0)

__device__ __forceinline__ u16 f2bf(float f) {
  unsigned int u = __float_as_uint(f);
  return (u16)((u + 0x7FFFu + ((u >> 16) & 1u)) >> 16);
}
__device__ __forceinline__ u32 pack2bf(float a, float b) {
  return (u32)f2bf(a) | ((u32)f2bf(b) << 16);
}
__device__ __forceinline__ ull pack4bf(float a, float b, float c, float d) {
  return (ull)pack2bf(a, b) | ((ull)pack2bf(c, d) << 32);
}
__device__ __forceinline__ float bf2f(u32 v) { return __uint_as_float(v << 16); }

#define GLL16(src, dst)                                                        \
  __builtin_amdgcn_global_load_lds(                                            \
      (const __attribute__((address_space(1))) void*)(src),                    \
      (__attribute__((address_space(3))) void*)(dst), 16, 0, 0)

// ---------------------------------------------------------------------------
// ws layout (bytes)
#define OFF_XT   0ull            // xT bf16 [36864][512]; later zp splits 0,1
#define OFF_FG   37748736ull     // fg bf16 [36864][512] (f at o<256, g at 256..511); later z bf16
#define OFF_HT   75497472ull     // hT bf16 [16][256][2304]
#define OFF_WB   94371840ull     // Wfgh bf16 [768][512]
#define OFF_VW   95158272ull     // v_w bf16 [512][256]
#define OFF_BIAS 95420416ull     // bias f32 [768]
#define ZP_ELEMS (9437184ull)    // 36864*256 per split

// ---------------------------------------------------------------------------
// K0: fold BN into conv weights, convert weights to bf16.
__global__ __launch_bounds__(64) void k_prep(
    const float* __restrict__ f_w, const float* __restrict__ f_b2, const float* __restrict__ f_gamma,
    const float* __restrict__ f_beta, const float* __restrict__ f_mean, const float* __restrict__ f_var,
    const float* __restrict__ g_w, const float* __restrict__ g_b2, const float* __restrict__ g_gamma,
    const float* __restrict__ g_beta, const float* __restrict__ g_mean, const float* __restrict__ g_var,
    const float* __restrict__ h_w, const float* __restrict__ h_b2, const float* __restrict__ v_w,
    u16* __restrict__ Wb, u16* __restrict__ vwb, float* __restrict__ biasb)
{
  const int bid = blockIdx.x, t = threadIdx.x;
  if (bid < 768) {
    const int o = bid;
    const float* wsrc;
    float scale, bias_v;
    if (o < 256) {
      scale = f_gamma[o] * rsqrtf(f_var[o] + 1e-5f);
      wsrc = f_w + o * 512;
      bias_v = (f_b2[o] - f_mean[o]) * scale + f_beta[o];
    } else if (o < 512) {
      const int i = o - 256;
      scale = g_gamma[i] * rsqrtf(g_var[i] + 1e-5f);
      wsrc = g_w + i * 512;
      bias_v = (g_b2[i] - g_mean[i]) * scale + g_beta[i];
    } else {
      const int i = o - 512;
      scale = 1.0f;
      wsrc = h_w + i * 512;
      bias_v = h_b2[i];
    }
#pragma unroll
    for (int j = 0; j < 8; ++j)
      Wb[o * 512 + t * 8 + j] = f2bf(wsrc[t * 8 + j] * scale);
    if (t == 0) biasb[o] = bias_v;
  } else {
    const int r = bid - 768;
#pragma unroll
    for (int j = 0; j < 4; ++j)
      vwb[r * 256 + t * 4 + j] = f2bf(v_w[r * 256 + t * 4 + j]);
  }
}

// ---------------------------------------------------------------------------
// K1: x [b][c][n] f32  ->  xT [b*n][c] bf16   (64x64 tiles via LDS)
__global__ __launch_bounds__(256) void k_trx(const float* __restrict__ x, u16* __restrict__ xT)
{
  __shared__ __align__(16) u16 T[64 * 72];
  const int t = threadIdx.x;
  const int n0 = blockIdx.x * 64, c0 = blockIdx.y * 64, b = blockIdx.z;
#pragma unroll
  for (int it = 0; it < 4; ++it) {
    const int cr = it * 16 + (t >> 4);
    const int nc = (t & 15) * 4;
    const float4 v = *(const float4*)(x + ((size_t)(b * 512 + c0 + cr)) * N_ + n0 + nc);
    T[cr * 72 + nc + 0] = f2bf(v.x);
    T[cr * 72 + nc + 1] = f2bf(v.y);
    T[cr * 72 + nc + 2] = f2bf(v.z);
    T[cr * 72 + nc + 3] = f2bf(v.w);
  }
  __syncthreads();
#pragma unroll
  for (int it = 0; it < 2; ++it) {
    const int nr = it * 32 + (t >> 3);
    const int ch = t & 7;
    s16x8 val;
#pragma unroll
    for (int j = 0; j < 8; ++j) val[j] = (short)T[(ch * 8 + j) * 72 + nr];
    *(s16x8*)(xT + ((size_t)(b * N_ + n0 + nr)) * 512 + c0 + ch * 8) = val;
  }
}

// ---------------------------------------------------------------------------
// K2: GEMM1  D[o][n] = Wfgh[o][c] * x[c][n]  (+bias, relu for o<512)
__global__ __launch_bounds__(256) void k_gemm1(const u16* __restrict__ Wb, const u16* __restrict__ xT,
                                               const float* __restrict__ biasb,
                                               u16* __restrict__ fg, u16* __restrict__ hT)
{
  __shared__ __align__(16) u16 Al[128 * 64];
  __shared__ __align__(16) u16 Bl[128 * 64];
  const int tid = threadIdx.x, lane = tid & 63, w = tid >> 6;
  const int wr = w >> 1, wc = w & 1;
  const int row16 = lane & 15, g = lane >> 4;
  const int nt = blockIdx.x, mt = blockIdx.y;
  const int nbase = nt * 128;
  const int sr = lane >> 3, sj = lane & 7;

  f32x4 acc[4][4] = {};

  for (int kt = 0; kt < 8; ++kt) {
#pragma unroll
    for (int s = 0; s < 4; ++s) {
      const int r = s * 32 + w * 8 + sr;
      GLL16(Wb + (size_t)(mt * 128 + r) * 512 + kt * 64 + ((sj ^ (r & 7)) * 8), Al + (s * 32 + w * 8) * 64);
    }
#pragma unroll
    for (int s = 0; s < 4; ++s) {
      const int r = s * 32 + w * 8 + sr;
      GLL16(xT + (size_t)(nbase + r) * 512 + kt * 64 + ((sj ^ (r & 7)) * 8), Bl + (s * 32 + w * 8) * 64);
    }
    __syncthreads();
#pragma unroll
    for (int kk = 0; kk < 2; ++kk) {
      s16x8 a[4], b[4];
#pragma unroll
      for (int m = 0; m < 4; ++m) {
        const int row = wr * 64 + m * 16 + row16;
        a[m] = *(const s16x8*)(Al + row * 64 + (((kk * 4 + g) ^ (row & 7)) * 8));
      }
#pragma unroll
      for (int n = 0; n < 4; ++n) {
        const int row = wc * 64 + n * 16 + row16;
        b[n] = *(const s16x8*)(Bl + row * 64 + (((kk * 4 + g) ^ (row & 7)) * 8));
      }
#pragma unroll
      for (int m = 0; m < 4; ++m)
#pragma unroll
        for (int n = 0; n < 4; ++n)
          acc[m][n] = MFMA16(a[m], b[n], acc[m][n]);
    }
    __syncthreads();
  }

  const int bt = nbase / N_;
  if (mt < 4) {
#pragma unroll
    for (int m = 0; m < 4; ++m) {
      const int o0 = mt * 128 + wr * 64 + m * 16 + g * 4;
      const float b0 = biasb[o0], b1 = biasb[o0 + 1], b2 = biasb[o0 + 2], b3 = biasb[o0 + 3];
#pragma unroll
      for (int n = 0; n < 4; ++n) {
        const int nn = nbase + wc * 64 + n * 16 + row16;
        const f32x4 v = acc[m][n];
        *(ull*)(fg + (size_t)nn * 512 + o0) =
            pack4bf(fmaxf(v[0] + b0, 0.f), fmaxf(v[1] + b1, 0.f),
                    fmaxf(v[2] + b2, 0.f), fmaxf(v[3] + b3, 0.f));
      }
    }
  } else {
#pragma unroll
    for (int m = 0; m < 4; ++m) {
      const int o0 = mt * 128 + wr * 64 + m * 16 + g * 4;
#pragma unroll
      for (int n = 0; n < 4; ++n) {
        const int nn = nbase + wc * 64 + n * 16 + row16;
        const int nl = nn - bt * N_;
#pragma unroll
        for (int i = 0; i < 4; ++i)
          hT[(size_t)(bt * 256 + (o0 - 512) + i) * N_ + nl] = f2bf(acc[m][n][i] + biasb[o0 + i]);
      }
    }
  }
}

// ---------------------------------------------------------------------------
// K3: flash attention v2.  128 q/block (32 q/wave), KV tile 32, dbuf K/V,
//   S^T = mfma(K,Q) so P quads stay in-lane -> packed b64 P writes; PV is
//   c-split across waves (each wave: 64 c x 128 q).  KV split 4-way across
//   blockIdx.z; bf16 partial z + f32 partial denom; combined later.
__global__ __launch_bounds__(256, 2) void k_flash2(const u16* __restrict__ fg, const u16* __restrict__ hT,
                                                   u16* __restrict__ zpA, u16* __restrict__ zpB,
                                                   float* __restrict__ dp)
{
  __shared__ __align__(16) u16 Kl[2][32 * 256];   // [kv][c], 16B-chunk swz ^(r&7)
  __shared__ __align__(16) u16 Vl[2][256 * 32];   // V^T [c][kv], chunk swz ^(c&3)
  __shared__ __align__(16) u16 Pl[128 * 32];      // P [q][kv], chunk swz ^(q&3)
  const int tid = threadIdx.x, lane = tid & 63, w = tid >> 6;
  const int c16 = lane & 15, g = lane >> 4;
  const int b = blockIdx.y, sp = blockIdx.z;
  const int qb = blockIdx.x * 128;

  // Q as B-operand frags (col = lane&15): rows qb + w*32 + qt*16 + c16
  s16x8 qf[2][8];
#pragma unroll
  for (int qt = 0; qt < 2; ++qt) {
    const u16* qbase = fg + (size_t)(b * N_ + qb + w * 32 + qt * 16 + c16) * 512;
#pragma unroll
    for (int kt = 0; kt < 8; ++kt) qf[qt][kt] = *(const s16x8*)(qbase + kt * 32 + g * 8);
  }

  f32x4 accz[4][8] = {};            // [ct][qt']: c = w*64+ct*16+..., q block-rel
  float dsum[2] = {0.f, 0.f};

  const int kr = lane >> 5, kj = lane & 31;   // K stage: 2 rows/call
  const int vr = lane >> 2, vch = lane & 3;   // V stage: 16 rows/call

  const int t0 = sp * 18;
  {  // prologue: stage tile 0 into buf 0
    const int m0 = t0 * 32;
#pragma unroll
    for (int s = 0; s < 4; ++s) {
      const int rb = w * 8 + s * 2, r = rb + kr;
      GLL16(fg + (size_t)(b * N_ + m0 + r) * 512 + 256 + ((kj ^ (r & 7)) * 8), &Kl[0][rb * 256]);
    }
#pragma unroll
    for (int s = 0; s < 4; ++s) {
      const int c0 = w * 64 + s * 16, r = c0 + vr;
      GLL16(hT + (size_t)(b * 256 + r) * N_ + m0 + ((vch ^ (r & 3)) * 8), &Vl[0][c0 * 32]);
    }
  }

  for (int it = 0; it < 18; ++it) {
    const int cur = it & 1;
    __syncthreads();   // drains vmcnt: tile[cur] ready; prev-iter readers done

    // ---- S^T = K * Q   (D[kv][q]: row = kv = 4g+i (+16kvt), col = q = c16)
    f32x4 sT[2][2] = {};
#pragma unroll
    for (int kvt = 0; kvt < 2; ++kvt) {
      const int krow = kvt * 16 + c16;
#pragma unroll
      for (int kt = 0; kt < 8; ++kt) {
        const s16x8 kf = *(const s16x8*)(&Kl[cur][krow * 256 + (((kt * 4 + g) ^ (krow & 7)) * 8)]);
        sT[kvt][0] = MFMA16(kf, qf[0][kt], sT[kvt][0]);
        sT[kvt][1] = MFMA16(kf, qf[1][kt], sT[kvt][1]);
      }
    }
    // ---- exp + packed P write (kv quad 16*kvt+4g.. at row q) + denom
#pragma unroll
    for (int kvt = 0; kvt < 2; ++kvt)
#pragma unroll
      for (int qt = 0; qt < 2; ++qt) {
        const float p0 = exp2f(sT[kvt][qt][0] * K1F - K2F);
        const float p1 = exp2f(sT[kvt][qt][1] * K1F - K2F);
        const float p2 = exp2f(sT[kvt][qt][2] * K1F - K2F);
        const float p3 = exp2f(sT[kvt][qt][3] * K1F - K2F);
        dsum[qt] += (p0 + p1) + (p2 + p3);
        const int qblk = w * 32 + qt * 16 + c16;
        const int chunk = (2 * kvt + (g >> 1)) ^ (qblk & 3);
        *(ull*)((char*)Pl + qblk * 64 + chunk * 16 + (g & 1) * 8) =
            (ull)pack2bf(p0, p1) | ((ull)pack2bf(p2, p3) << 32);
      }
    __syncthreads();   // P visible to all waves (no vm ops pending -> no stall)

    if (it + 1 < 18) {   // stage next tile; drained by next iter's top barrier
      const int m0 = (t0 + it + 1) * 32;
      const int nb = cur ^ 1;
#pragma unroll
      for (int s = 0; s < 4; ++s) {
        const int rb = w * 8 + s * 2, r = rb + kr;
        GLL16(fg + (size_t)(b * N_ + m0 + r) * 512 + 256 + ((kj ^ (r & 7)) * 8), &Kl[nb][rb * 256]);
      }
#pragma unroll
      for (int s = 0; s < 4; ++s) {
        const int c0 = w * 64 + s * 16, r = c0 + vr;
        GLL16(hT + (size_t)(b * 256 + r) * N_ + m0 + ((vch ^ (r & 3)) * 8), &Vl[nb][c0 * 32]);
      }
    }

    // ---- PV: accz[ct][qt'] += V^T(c-slice) * P^T   (2x4 qt blocking)
#pragma unroll
    for (int qh = 0; qh < 2; ++qh) {
      s16x8 pb[4];
#pragma unroll
      for (int q4 = 0; q4 < 4; ++q4) {
        const int qblk = (qh * 4 + q4) * 16 + c16;
        pb[q4] = *(const s16x8*)((char*)Pl + qblk * 64 + ((g ^ (qblk & 3)) * 16));
      }
#pragma unroll
      for (int ct = 0; ct < 4; ++ct) {
        const int c = w * 64 + ct * 16 + c16;
        const s16x8 vf = *(const s16x8*)(&Vl[cur][c * 32 + ((g ^ (c & 3)) * 8)]);
#pragma unroll
        for (int q4 = 0; q4 < 4; ++q4)
          accz[ct][qh * 4 + q4] = MFMA16(vf, pb[q4], accz[ct][qh * 4 + q4]);
      }
    }
  }

  // ---- epilogue: reduce denom across g-groups, store partials
#pragma unroll
  for (int qt = 0; qt < 2; ++qt) {
    float d = dsum[qt];
    d += __shfl_xor(d, 16);
    d += __shfl_xor(d, 32);
    dsum[qt] = d;
  }
  if (lane < 16) {
    dp[(size_t)sp * NT_ + b * N_ + qb + w * 32 + lane] = dsum[0];
    dp[(size_t)sp * NT_ + b * N_ + qb + w * 32 + 16 + lane] = dsum[1];
  }
  u16* zp = (sp < 2) ? (zpA + (size_t)sp * ZP_ELEMS) : (zpB + (size_t)(sp - 2) * ZP_ELEMS);
#pragma unroll
  for (int ct = 0; ct < 4; ++ct) {
    const int c = w * 64 + ct * 16 + g * 4;
#pragma unroll
    for (int qt = 0; qt < 8; ++qt) {
      const int n = qb + qt * 16 + c16;
      *(ull*)(zp + (size_t)(b * N_ + n) * 256 + c) =
          pack4bf(accz[ct][qt][0], accz[ct][qt][1], accz[ct][qt][2], accz[ct][qt][3]);
    }
  }
}

// ---------------------------------------------------------------------------
// K3b: combine partials:  z[n][c] = (sum_s zp[s][n][c]) / (sum_s dp[s][n])
__global__ __launch_bounds__(256) void k_combine(const u16* __restrict__ zpA, const u16* __restrict__ zpB,
                                                 const float* __restrict__ dp, u16* __restrict__ zout)
{
  const int gid = blockIdx.x * 256 + threadIdx.x;
  const int n = gid >> 6;
  const int c = (gid & 63) * 4;
  const float inv = 1.0f / (dp[n] + dp[NT_ + n] + dp[2 * NT_ + n] + dp[3 * NT_ + n]);
  float a0 = 0.f, a1 = 0.f, a2 = 0.f, a3 = 0.f;
#pragma unroll
  for (int s = 0; s < 4; ++s) {
    const u16* zp = (s < 2) ? (zpA + (size_t)s * ZP_ELEMS) : (zpB + (size_t)(s - 2) * ZP_ELEMS);
    const ull v = *(const ull*)(zp + (size_t)n * 256 + c);
    a0 += bf2f((u32)(v & 0xffff));
    a1 += bf2f((u32)((v >> 16) & 0xffff));
    a2 += bf2f((u32)((v >> 32) & 0xffff));
    a3 += bf2f((u32)(v >> 48));
  }
  *(ull*)(zout + (size_t)n * 256 + c) = pack4bf(a0 * inv, a1 * inv, a2 * inv, a3 * inv);
}

// ---------------------------------------------------------------------------
// K4: GEMM2  out[b][o][n] = v_w[o][c] * z[c][n] + v_b[o] + x[b][o][n]
__global__ __launch_bounds__(256) void k_gemm2(const u16* __restrict__ zb, const u16* __restrict__ vwb,
                                               const float* __restrict__ v_b, const float* __restrict__ x,
                                               float* __restrict__ out)
{
  __shared__ __align__(16) u16 Al[128 * 64];
  __shared__ __align__(16) u16 Bl[128 * 64];
  const int tid = threadIdx.x, lane = tid & 63, w = tid >> 6;
  const int wr = w >> 1, wc = w & 1;
  const int row16 = lane & 15, g = lane >> 4;
  const int nt = blockIdx.x, ot = blockIdx.y;
  const int nbase = nt * 128;
  const int sr = lane >> 3, sj = lane & 7;

  f32x4 acc[4][4] = {};

  for (int kt = 0; kt < 4; ++kt) {
#pragma unroll
    for (int s = 0; s < 4; ++s) {
      const int r = s * 32 + w * 8 + sr;
      GLL16(zb + (size_t)(nbase + r) * 256 + kt * 64 + ((sj ^ (r & 7)) * 8), Al + (s * 32 + w * 8) * 64);
    }
#pragma unroll
    for (int s = 0; s < 4; ++s) {
      const int r = s * 32 + w * 8 + sr;
      GLL16(vwb + (size_t)(ot * 128 + r) * 256 + kt * 64 + ((sj ^ (r & 7)) * 8), Bl + (s * 32 + w * 8) * 64);
    }
    __syncthreads();
#pragma unroll
    for (int kk = 0; kk < 2; ++kk) {
      s16x8 a[4], b[4];
#pragma unroll
      for (int m = 0; m < 4; ++m) {
        const int row = wr * 64 + m * 16 + row16;
        a[m] = *(const s16x8*)(Al + row * 64 + (((kk * 4 + g) ^ (row & 7)) * 8));
      }
#pragma unroll
      for (int n = 0; n < 4; ++n) {
        const int row = wc * 64 + n * 16 + row16;
        b[n] = *(const s16x8*)(Bl + row * 64 + (((kk * 4 + g) ^ (row & 7)) * 8));
      }
#pragma unroll
      for (int m = 0; m < 4; ++m)
#pragma unroll
        for (int n = 0; n < 4; ++n)
          acc[m][n] = MFMA16(a[m], b[n], acc[m][n]);
    }
    __syncthreads();
  }

  const int bt = nbase / N_;
#pragma unroll
  for (int m = 0; m < 4; ++m) {
    const int nl0 = (nbase - bt * N_) + wr * 64 + m * 16 + g * 4;
#pragma unroll
    for (int n = 0; n < 4; ++n) {
      const int o = ot * 128 + wc * 64 + n * 16 + row16;
      const float vb = v_b[o];
      const size_t off = (size_t)(bt * 512 + o) * N_ + nl0;
      const float4 xv = *(const float4*)(x + off);
      float4 r;
      r.x = acc[m][n][0] + vb + xv.x;
      r.y = acc[m][n][1] + vb + xv.y;
      r.z = acc[m][n][2] + vb + xv.z;
      r.w = acc[m][n][3] + vb + xv.w;
      *(float4*)(out + off) = r;
    }
  }
}

// ---------------------------------------------------------------------------
extern "C" void kernel_launch(void* const* d_in, const int* in_sizes, int n_in,
                              void* d_out, int out_size, void* d_ws, size_t ws_size,
                              hipStream_t stream)
{
  const float* x       = (const float*)d_in[0];
  const float* f_w     = (const float*)d_in[1];
  const float* f_b     = (const float*)d_in[2];
  const float* f_gamma = (const float*)d_in[3];
  const float* f_beta  = (const float*)d_in[4];
  const float* f_mean  = (const float*)d_in[5];
  const float* f_var   = (const float*)d_in[6];
  const float* g_w     = (const float*)d_in[7];
  const float* g_b     = (const float*)d_in[8];
  const float* g_gamma = (const float*)d_in[9];
  const float* g_beta  = (const float*)d_in[10];
  const float* g_mean  = (const float*)d_in[11];
  const float* g_var   = (const float*)d_in[12];
  const float* h_w     = (const float*)d_in[13];
  const float* h_b     = (const float*)d_in[14];
  const float* v_w     = (const float*)d_in[15];
  const float* v_b     = (const float*)d_in[16];

  char* ws = (char*)d_ws;
  u16*  xT    = (u16*)(ws + OFF_XT);
  u16*  fg    = (u16*)(ws + OFF_FG);
  u16*  hT    = (u16*)(ws + OFF_HT);
  u16*  Wb    = (u16*)(ws + OFF_WB);
  u16*  vwb   = (u16*)(ws + OFF_VW);
  float* biasb = (float*)(ws + OFF_BIAS);
  float* out  = (float*)d_out;

  // flash partial buffers: splits 0,1 over the dead xT region; splits 2,3 +
  // denominators in d_out (fully overwritten by k_gemm2 afterwards).
  u16*  zpA = (u16*)(ws + OFF_XT);
  u16*  zpB = (u16*)d_out;
  float* dp = (float*)((char*)d_out + 37748736ull);
  u16*  z   = (u16*)(ws + OFF_FG);   // combined z overwrites dead fg region

  hipLaunchKernelGGL(k_prep, dim3(1280), dim3(64), 0, stream,
                     f_w, f_b, f_gamma, f_beta, f_mean, f_var,
                     g_w, g_b, g_gamma, g_beta, g_mean, g_var,
                     h_w, h_b, v_w, Wb, vwb, biasb);
  hipLaunchKernelGGL(k_trx, dim3(36, 8, 16), dim3(256), 0, stream, x, xT);
  hipLaunchKernelGGL(k_gemm1, dim3(288, 6), dim3(256), 0, stream, Wb, xT, biasb, fg, hT);
  hipLaunchKernelGGL(k_flash2, dim3(18, 16, 4), dim3(256), 0, stream, fg, hT, zpA, zpB, dp);
  hipLaunchKernelGGL(k_combine, dim3(9216), dim3(256), 0, stream, zpA, zpB, dp, z);
  hipLaunchKernelGGL(k_gemm2, dim3(288, 4), dim3(256), 0, stream, z, vwb, v_b, x, out);
}

// Round 3
// 299.589 us; speedup vs baseline: 1.2702x; 1.1967x over previous
//
#include <hip/hip_runtime.h>

// ---------------------------------------------------------------------------
// SOABlock: f,g = BN(ReLU(1x1conv)), h = 1x1conv, attn = softmax(f^T g /16),
// z = attn @ h^T, out = v(z) + x.   B=16, C=512, MID=256, N=48*48=2304.
// ---------------------------------------------------------------------------

#define B_    16
#define C_    512
#define MID_  256
#define N_    2304
#define NT_   (B_ * N_)          // 36864

typedef unsigned short u16;
typedef unsigned int   u32;
typedef unsigned long long ull;
typedef short s16x8 __attribute__((ext_vector_type(8)));   // 8 bf16 (4 VGPR)
typedef float f32x4 __attribute__((ext_vector_type(4)));
typedef float f32x16 __attribute__((ext_vector_type(16)));

// exp constants: P = exp(S/16 - 20) = exp2(S*K1F - K2F)
#define K1F 0.09016844005556021f
#define K2F 28.853900817779268f

#define MFMA16(a, b, c) __builtin_amdgcn_mfma_f32_16x16x32_bf16(a, b, c, 0, 0, 0)
#define MFMA32(a, b, c) __builtin_amdgcn_mfma_f32_32x32x16_bf16(a, b, c, 0, 0, 0)

__device__ __forceinline__ u16 f2bf(float f) {
  unsigned int u = __float_as_uint(f);
  return (u16)((u + 0x7FFFu + ((u >> 16) & 1u)) >> 16);
}
__device__ __forceinline__ u32 pack2bf(float a, float b) {
  return (u32)f2bf(a) | ((u32)f2bf(b) << 16);
}
__device__ __forceinline__ ull pack4bf(float a, float b, float c, float d) {
  return (ull)pack2bf(a, b) | ((ull)pack2bf(c, d) << 32);
}
// truncating pack (P values; ~0.2% bias is fine, saves VALU)
__device__ __forceinline__ u32 pack2t(float a, float b) {
  return (__float_as_uint(a) >> 16) | (__float_as_uint(b) & 0xffff0000u);
}
__device__ __forceinline__ float bf2f(u32 v) { return __uint_as_float(v << 16); }

#define GLL16(src, dst)                                                        \
  __builtin_amdgcn_global_load_lds(                                            \
      (const __attribute__((address_space(1))) void*)(src),                    \
      (__attribute__((address_space(3))) void*)(dst), 16, 0, 0)

// ---------------------------------------------------------------------------
// ws layout (bytes)
#define OFF_XT   0ull            // xT bf16 [36864][512]; later zp splits 0,1
#define OFF_FG   37748736ull     // fg bf16 [36864][512]; later combined z bf16
#define OFF_HT   75497472ull     // hT bf16 [16][256][2304]
#define OFF_WB   94371840ull     // Wfgh bf16 [768][512]
#define OFF_VW   95158272ull     // v_w bf16 [512][256]
#define OFF_BIAS 95420416ull     // bias f32 [768]
#define ZP_ELEMS (9437184ull)    // 36864*256 per split

// ---------------------------------------------------------------------------
// K0: fold BN into conv weights, convert weights to bf16.
__global__ __launch_bounds__(64) void k_prep(
    const float* __restrict__ f_w, const float* __restrict__ f_b2, const float* __restrict__ f_gamma,
    const float* __restrict__ f_beta, const float* __restrict__ f_mean, const float* __restrict__ f_var,
    const float* __restrict__ g_w, const float* __restrict__ g_b2, const float* __restrict__ g_gamma,
    const float* __restrict__ g_beta, const float* __restrict__ g_mean, const float* __restrict__ g_var,
    const float* __restrict__ h_w, const float* __restrict__ h_b2, const float* __restrict__ v_w,
    u16* __restrict__ Wb, u16* __restrict__ vwb, float* __restrict__ biasb)
{
  const int bid = blockIdx.x, t = threadIdx.x;
  if (bid < 768) {
    const int o = bid;
    const float* wsrc;
    float scale, bias_v;
    if (o < 256) {
      scale = f_gamma[o] * rsqrtf(f_var[o] + 1e-5f);
      wsrc = f_w + o * 512;
      bias_v = (f_b2[o] - f_mean[o]) * scale + f_beta[o];
    } else if (o < 512) {
      const int i = o - 256;
      scale = g_gamma[i] * rsqrtf(g_var[i] + 1e-5f);
      wsrc = g_w + i * 512;
      bias_v = (g_b2[i] - g_mean[i]) * scale + g_beta[i];
    } else {
      const int i = o - 512;
      scale = 1.0f;
      wsrc = h_w + i * 512;
      bias_v = h_b2[i];
    }
#pragma unroll
    for (int j = 0; j < 8; ++j)
      Wb[o * 512 + t * 8 + j] = f2bf(wsrc[t * 8 + j] * scale);
    if (t == 0) biasb[o] = bias_v;
  } else {
    const int r = bid - 768;
#pragma unroll
    for (int j = 0; j < 4; ++j)
      vwb[r * 256 + t * 4 + j] = f2bf(v_w[r * 256 + t * 4 + j]);
  }
}

// ---------------------------------------------------------------------------
// K1: x [b][c][n] f32  ->  xT [b*n][c] bf16   (64x64 tiles via LDS)
__global__ __launch_bounds__(256) void k_trx(const float* __restrict__ x, u16* __restrict__ xT)
{
  __shared__ __align__(16) u16 T[64 * 72];
  const int t = threadIdx.x;
  const int n0 = blockIdx.x * 64, c0 = blockIdx.y * 64, b = blockIdx.z;
#pragma unroll
  for (int it = 0; it < 4; ++it) {
    const int cr = it * 16 + (t >> 4);
    const int nc = (t & 15) * 4;
    const float4 v = *(const float4*)(x + ((size_t)(b * 512 + c0 + cr)) * N_ + n0 + nc);
    T[cr * 72 + nc + 0] = f2bf(v.x);
    T[cr * 72 + nc + 1] = f2bf(v.y);
    T[cr * 72 + nc + 2] = f2bf(v.z);
    T[cr * 72 + nc + 3] = f2bf(v.w);
  }
  __syncthreads();
#pragma unroll
  for (int it = 0; it < 2; ++it) {
    const int nr = it * 32 + (t >> 3);
    const int ch = t & 7;
    s16x8 val;
#pragma unroll
    for (int j = 0; j < 8; ++j) val[j] = (short)T[(ch * 8 + j) * 72 + nr];
    *(s16x8*)(xT + ((size_t)(b * N_ + n0 + nr)) * 512 + c0 + ch * 8) = val;
  }
}

// ---------------------------------------------------------------------------
// K2: GEMM1  D[o][n] = Wfgh[o][c] * x[c][n]  (+bias, relu for o<512)
__global__ __launch_bounds__(256) void k_gemm1(const u16* __restrict__ Wb, const u16* __restrict__ xT,
                                               const float* __restrict__ biasb,
                                               u16* __restrict__ fg, u16* __restrict__ hT)
{
  __shared__ __align__(16) u16 Al[128 * 64];
  __shared__ __align__(16) u16 Bl[128 * 64];
  const int tid = threadIdx.x, lane = tid & 63, w = tid >> 6;
  const int wr = w >> 1, wc = w & 1;
  const int row16 = lane & 15, g = lane >> 4;
  const int nt = blockIdx.x, mt = blockIdx.y;
  const int nbase = nt * 128;
  const int sr = lane >> 3, sj = lane & 7;

  f32x4 acc[4][4] = {};

  for (int kt = 0; kt < 8; ++kt) {
#pragma unroll
    for (int s = 0; s < 4; ++s) {
      const int r = s * 32 + w * 8 + sr;
      GLL16(Wb + (size_t)(mt * 128 + r) * 512 + kt * 64 + ((sj ^ (r & 7)) * 8), Al + (s * 32 + w * 8) * 64);
    }
#pragma unroll
    for (int s = 0; s < 4; ++s) {
      const int r = s * 32 + w * 8 + sr;
      GLL16(xT + (size_t)(nbase + r) * 512 + kt * 64 + ((sj ^ (r & 7)) * 8), Bl + (s * 32 + w * 8) * 64);
    }
    __syncthreads();
#pragma unroll
    for (int kk = 0; kk < 2; ++kk) {
      s16x8 a[4], b[4];
#pragma unroll
      for (int m = 0; m < 4; ++m) {
        const int row = wr * 64 + m * 16 + row16;
        a[m] = *(const s16x8*)(Al + row * 64 + (((kk * 4 + g) ^ (row & 7)) * 8));
      }
#pragma unroll
      for (int n = 0; n < 4; ++n) {
        const int row = wc * 64 + n * 16 + row16;
        b[n] = *(const s16x8*)(Bl + row * 64 + (((kk * 4 + g) ^ (row & 7)) * 8));
      }
#pragma unroll
      for (int m = 0; m < 4; ++m)
#pragma unroll
        for (int n = 0; n < 4; ++n)
          acc[m][n] = MFMA16(a[m], b[n], acc[m][n]);
    }
    __syncthreads();
  }

  const int bt = nbase / N_;
  if (mt < 4) {
#pragma unroll
    for (int m = 0; m < 4; ++m) {
      const int o0 = mt * 128 + wr * 64 + m * 16 + g * 4;
      const float b0 = biasb[o0], b1 = biasb[o0 + 1], b2 = biasb[o0 + 2], b3 = biasb[o0 + 3];
#pragma unroll
      for (int n = 0; n < 4; ++n) {
        const int nn = nbase + wc * 64 + n * 16 + row16;
        const f32x4 v = acc[m][n];
        *(ull*)(fg + (size_t)nn * 512 + o0) =
            pack4bf(fmaxf(v[0] + b0, 0.f), fmaxf(v[1] + b1, 0.f),
                    fmaxf(v[2] + b2, 0.f), fmaxf(v[3] + b3, 0.f));
      }
    }
  } else {
#pragma unroll
    for (int m = 0; m < 4; ++m) {
      const int o0 = mt * 128 + wr * 64 + m * 16 + g * 4;
#pragma unroll
      for (int n = 0; n < 4; ++n) {
        const int nn = nbase + wc * 64 + n * 16 + row16;
        const int nl = nn - bt * N_;
#pragma unroll
        for (int i = 0; i < 4; ++i)
          hT[(size_t)(bt * 256 + (o0 - 512) + i) * N_ + nl] = f2bf(acc[m][n][i] + biasb[o0 + i]);
      }
    }
  }
}

// ---------------------------------------------------------------------------
// K3: flash attention v3 — in-register P via 32x32 MFMA.
//   128 q/block, 4 waves x 32 q each; KV tile 32, K/V double-buffered in LDS,
//   ONE barrier per iteration (stage issued right after it -> full-iter
//   overlap).  S^T = mfma32(K, Q): lane holds P[kv-quads][q]; PV B-frag built
//   in-register with packs + shfl_xor(32).  KV split 2-way (blockIdx encodes
//   batch/qb/sp with XCD-locality swizzle: each XCD works on 2 batches).
__global__ __launch_bounds__(256, 2) void k_flash3(const u16* __restrict__ fg, const u16* __restrict__ hT,
                                                   u16* __restrict__ zp0, u16* __restrict__ zp1,
                                                   float* __restrict__ dp)
{
  __shared__ __align__(16) u16 Sh[32768];   // 64KB: K[2]@0,8192  V[2]@16384,24576
  const int tid = threadIdx.x, lane = tid & 63, w = tid >> 6;
  const int q5 = lane & 31, hi = lane >> 5;

  // XCD-locality block swizzle: 576 blocks; xcd = L&7 handles batches {2x,2x+1}
  const int L = blockIdx.x;
  const int xcd = L & 7, s = L >> 3;          // s 0..71
  const int b = xcd * 2 + (s >= 36 ? 1 : 0);
  const int j = (s >= 36) ? s - 36 : s;       // 0..35
  const int qb = (j % 18) * 128;
  const int sp = j / 18;                      // KV split id 0..1
  const int t0 = sp * 36;                     // first kv tile

  // Q fragments (B-operand): lane(q5,hi) holds Q[qrow][ks*16 + hi*8 .. +7]
  const int qrow = b * N_ + qb + w * 32 + q5;
  s16x8 qf[16];
#pragma unroll
  for (int ks = 0; ks < 16; ++ks)
    qf[ks] = *(const s16x8*)(fg + (size_t)qrow * 512 + ks * 16 + hi * 8);

  f32x16 accz[8] = {};     // z^T[c = ct*32 + rowpat][q = q5]
  float dsum = 0.f;

  // ---- staging helpers ----
  auto stageK = [&](int m0, int buf) {
    u16* dst = Sh + buf * 8192;
#pragma unroll
    for (int s2 = 0; s2 < 4; ++s2) {
      const int i = w * 4 + s2;
      const int r = 2 * i + hi;
      const int chp = lane & 31;
      const int ch = (chp & 24) | ((chp ^ (r & 7)) & 7);
      GLL16(fg + (size_t)(b * N_ + m0 + r) * 512 + 256 + ch * 8, dst + i * 512);
    }
  };
  auto stageV = [&](int m0, int buf) {
    u16* dst = Sh + 16384 + buf * 8192;
#pragma unroll
    for (int s2 = 0; s2 < 4; ++s2) {
      const int i = w * 4 + s2;
      const int r2 = i * 8 + (lane >> 3);
      const int ch = (lane & 7) ^ (r2 & 7);
      const int c = 2 * r2 + (ch >> 2);
      GLL16(hT + (size_t)(b * 256 + c) * N_ + m0 + (ch & 3) * 8, dst + i * 512);
    }
  };

  stageK(t0 * 32, 0);
  stageV(t0 * 32, 0);

  for (int it = 0; it < 36; ++it) {
    const int cur = it & 1;
    __syncthreads();                 // tile[cur] staged; prev readers of [cur^1] done
    if (it + 1 < 36) {               // prefetch next tile: full iteration to land
      stageK((t0 + it + 1) * 32, cur ^ 1);
      stageV((t0 + it + 1) * 32, cur ^ 1);
    }

    // ---- S^T[kv][q] = K * Q  (one 32x32 tile, K=256 in 16 steps)
    const u16* KL = Sh + cur * 8192;
    const int kvb = q5 * 256;        // A-row = kv = lane&31
    f32x16 sT = {};
    __builtin_amdgcn_s_setprio(1);
#pragma unroll
    for (int ks = 0; ks < 16; ++ks) {
      const int ch = ks * 2 + hi;
      const int chp = (ch & 24) | ((ch ^ (q5 & 7)) & 7);
      const s16x8 kf = *(const s16x8*)(KL + kvb + chp * 8);
      sT = MFMA32(kf, qf[ks], sT);
    }
    __builtin_amdgcn_s_setprio(0);

    // ---- exp + in-register P packs;  own quads O[2m+j], partner X via shfl
    u32 O[8], X[8];
    float lsum = 0.f;
#pragma unroll
    for (int m = 0; m < 4; ++m) {
      const float p0 = exp2f(sT[4 * m + 0] * K1F - K2F);
      const float p1 = exp2f(sT[4 * m + 1] * K1F - K2F);
      const float p2 = exp2f(sT[4 * m + 2] * K1F - K2F);
      const float p3 = exp2f(sT[4 * m + 3] * K1F - K2F);
      lsum += (p0 + p1) + (p2 + p3);
      O[2 * m] = pack2t(p0, p1);
      O[2 * m + 1] = pack2t(p2, p3);
    }
    dsum += lsum;
#pragma unroll
    for (int r = 0; r < 8; ++r) X[r] = (u32)__shfl_xor((int)O[r], 32);

    s16x8 pf[2];
#pragma unroll
    for (int h = 0; h < 2; ++h) {
      union { u32 wd[4]; s16x8 v; } u;
      u.wd[0] = hi ? X[4 * h + 2] : O[4 * h + 0];
      u.wd[1] = hi ? X[4 * h + 3] : O[4 * h + 1];
      u.wd[2] = hi ? O[4 * h + 2] : X[4 * h + 0];
      u.wd[3] = hi ? O[4 * h + 3] : X[4 * h + 1];
      pf[h] = u.v;
    }

    // ---- PV: accz[ct] += V^T(c-rows) * P   (8 c-tiles x 2 k-halves)
    const u16* VL = Sh + 16384 + cur * 8192;
    __builtin_amdgcn_s_setprio(1);
#pragma unroll
    for (int h = 0; h < 2; ++h)
#pragma unroll
      for (int ct = 0; ct < 8; ++ct) {
        const int c = ct * 32 + q5;
        const int r2 = c >> 1;
        const int ch = (c & 1) * 4 + h * 2 + hi;
        const int chp = ch ^ (r2 & 7);
        const s16x8 vf = *(const s16x8*)(VL + r2 * 64 + chp * 8);
        accz[ct] = MFMA32(vf, pf[h], accz[ct]);
      }
    __builtin_amdgcn_s_setprio(0);
  }

  // ---- denominator: combine hi-halves; lane q (hi=0) stores
  const float dtot = dsum + (float)__shfl_xor(dsum, 32);
  if (hi == 0)
    dp[(size_t)sp * NT_ + b * N_ + qb + w * 32 + q5] = dtot;

  // ---- transpose z^T -> [n][c] via per-wave LDS region, coalesced store
  __syncthreads();                   // everyone done with K/V LDS
  u16* R = Sh + w * 8192;            // 16KB per wave: [32 n][256 c], quad-swz
#pragma unroll
  for (int ct = 0; ct < 8; ++ct)
#pragma unroll
    for (int m = 0; m < 4; ++m) {
      const int quad = ct * 8 + 2 * m + hi;       // c-quad index (c = quad*4..)
      const int pos = quad ^ (q5 & 7);
      *(ull*)(R + q5 * 256 + pos * 4) =
          pack4bf(accz[ct][4 * m + 0], accz[ct][4 * m + 1],
                  accz[ct][4 * m + 2], accz[ct][4 * m + 3]);
    }
  u16* zp = sp ? zp1 : zp0;
  const size_t gbase = (size_t)(b * N_ + qb + w * 32) * 256;
#pragma unroll
  for (int n = 0; n < 32; ++n) {
    const ull v = *(const ull*)(R + n * 256 + ((lane ^ (n & 7)) & 63) * 4);
    *(ull*)(zp + gbase + n * 256 + lane * 4) = v;
  }
}

// ---------------------------------------------------------------------------
// K3b: combine partials:  z[n][c] = (zp0 + zp1) / (dp0 + dp1)
__global__ __launch_bounds__(256) void k_combine(const u16* __restrict__ zp0, const u16* __restrict__ zp1,
                                                 const float* __restrict__ dp, u16* __restrict__ zout)
{
  const int gid = blockIdx.x * 256 + threadIdx.x;
  const int n = gid >> 6;
  const int c = (gid & 63) * 4;
  const float inv = 1.0f / (dp[n] + dp[NT_ + n]);
  const ull va = *(const ull*)(zp0 + (size_t)n * 256 + c);
  const ull vb = *(const ull*)(zp1 + (size_t)n * 256 + c);
  const float a0 = bf2f((u32)(va & 0xffff)) + bf2f((u32)(vb & 0xffff));
  const float a1 = bf2f((u32)((va >> 16) & 0xffff)) + bf2f((u32)((vb >> 16) & 0xffff));
  const float a2 = bf2f((u32)((va >> 32) & 0xffff)) + bf2f((u32)((vb >> 32) & 0xffff));
  const float a3 = bf2f((u32)(va >> 48)) + bf2f((u32)(vb >> 48));
  *(ull*)(zout + (size_t)n * 256 + c) = pack4bf(a0 * inv, a1 * inv, a2 * inv, a3 * inv);
}

// ---------------------------------------------------------------------------
// K4: GEMM2  out[b][o][n] = v_w[o][c] * z[c][n] + v_b[o] + x[b][o][n]
__global__ __launch_bounds__(256) void k_gemm2(const u16* __restrict__ zb, const u16* __restrict__ vwb,
                                               const float* __restrict__ v_b, const float* __restrict__ x,
                                               float* __restrict__ out)
{
  __shared__ __align__(16) u16 Al[128 * 64];
  __shared__ __align__(16) u16 Bl[128 * 64];
  const int tid = threadIdx.x, lane = tid & 63, w = tid >> 6;
  const int wr = w >> 1, wc = w & 1;
  const int row16 = lane & 15, g = lane >> 4;
  const int nt = blockIdx.x, ot = blockIdx.y;
  const int nbase = nt * 128;
  const int sr = lane >> 3, sj = lane & 7;

  f32x4 acc[4][4] = {};

  for (int kt = 0; kt < 4; ++kt) {
#pragma unroll
    for (int s = 0; s < 4; ++s) {
      const int r = s * 32 + w * 8 + sr;
      GLL16(zb + (size_t)(nbase + r) * 256 + kt * 64 + ((sj ^ (r & 7)) * 8), Al + (s * 32 + w * 8) * 64);
    }
#pragma unroll
    for (int s = 0; s < 4; ++s) {
      const int r = s * 32 + w * 8 + sr;
      GLL16(vwb + (size_t)(ot * 128 + r) * 256 + kt * 64 + ((sj ^ (r & 7)) * 8), Bl + (s * 32 + w * 8) * 64);
    }
    __syncthreads();
#pragma unroll
    for (int kk = 0; kk < 2; ++kk) {
      s16x8 a[4], b[4];
#pragma unroll
      for (int m = 0; m < 4; ++m) {
        const int row = wr * 64 + m * 16 + row16;
        a[m] = *(const s16x8*)(Al + row * 64 + (((kk * 4 + g) ^ (row & 7)) * 8));
      }
#pragma unroll
      for (int n = 0; n < 4; ++n) {
        const int row = wc * 64 + n * 16 + row16;
        b[n] = *(const s16x8*)(Bl + row * 64 + (((kk * 4 + g) ^ (row & 7)) * 8));
      }
#pragma unroll
      for (int m = 0; m < 4; ++m)
#pragma unroll
        for (int n = 0; n < 4; ++n)
          acc[m][n] = MFMA16(a[m], b[n], acc[m][n]);
    }
    __syncthreads();
  }

  const int bt = nbase / N_;
#pragma unroll
  for (int m = 0; m < 4; ++m) {
    const int nl0 = (nbase - bt * N_) + wr * 64 + m * 16 + g * 4;
#pragma unroll
    for (int n = 0; n < 4; ++n) {
      const int o = ot * 128 + wc * 64 + n * 16 + row16;
      const float vb = v_b[o];
      const size_t off = (size_t)(bt * 512 + o) * N_ + nl0;
      const float4 xv = *(const float4*)(x + off);
      float4 r;
      r.x = acc[m][n][0] + vb + xv.x;
      r.y = acc[m][n][1] + vb + xv.y;
      r.z = acc[m][n][2] + vb + xv.z;
      r.w = acc[m][n][3] + vb + xv.w;
      *(float4*)(out + off) = r;
    }
  }
}

// ---------------------------------------------------------------------------
extern "C" void kernel_launch(void* const* d_in, const int* in_sizes, int n_in,
                              void* d_out, int out_size, void* d_ws, size_t ws_size,
                              hipStream_t stream)
{
  const float* x       = (const float*)d_in[0];
  const float* f_w     = (const float*)d_in[1];
  const float* f_b     = (const float*)d_in[2];
  const float* f_gamma = (const float*)d_in[3];
  const float* f_beta  = (const float*)d_in[4];
  const float* f_mean  = (const float*)d_in[5];
  const float* f_var   = (const float*)d_in[6];
  const float* g_w     = (const float*)d_in[7];
  const float* g_b     = (const float*)d_in[8];
  const float* g_gamma = (const float*)d_in[9];
  const float* g_beta  = (const float*)d_in[10];
  const float* g_mean  = (const float*)d_in[11];
  const float* g_var   = (const float*)d_in[12];
  const float* h_w     = (const float*)d_in[13];
  const float* h_b     = (const float*)d_in[14];
  const float* v_w     = (const float*)d_in[15];
  const float* v_b     = (const float*)d_in[16];

  char* ws = (char*)d_ws;
  u16*  xT    = (u16*)(ws + OFF_XT);
  u16*  fg    = (u16*)(ws + OFF_FG);
  u16*  hT    = (u16*)(ws + OFF_HT);
  u16*  Wb    = (u16*)(ws + OFF_WB);
  u16*  vwb   = (u16*)(ws + OFF_VW);
  float* biasb = (float*)(ws + OFF_BIAS);
  float* out  = (float*)d_out;

  // flash partials: both splits in the dead xT region; denominators in d_out
  // (gemm2 fully overwrites d_out afterwards).
  u16*  zp0 = (u16*)(ws + OFF_XT);
  u16*  zp1 = (u16*)(ws + OFF_XT + 2 * ZP_ELEMS);   // bytes = 2*elems
  float* dp = (float*)d_out;
  u16*  z   = (u16*)(ws + OFF_FG);   // combined z overwrites dead fg region

  hipLaunchKernelGGL(k_prep, dim3(1280), dim3(64), 0, stream,
                     f_w, f_b, f_gamma, f_beta, f_mean, f_var,
                     g_w, g_b, g_gamma, g_beta, g_mean, g_var,
                     h_w, h_b, v_w, Wb, vwb, biasb);
  hipLaunchKernelGGL(k_trx, dim3(36, 8, 16), dim3(256), 0, stream, x, xT);
  hipLaunchKernelGGL(k_gemm1, dim3(288, 6), dim3(256), 0, stream, Wb, xT, biasb, fg, hT);
  hipLaunchKernelGGL(k_flash3, dim3(576), dim3(256), 0, stream, fg, hT, zp0, zp1, dp);
  hipLaunchKernelGGL(k_combine, dim3(9216), dim3(256), 0, stream, zp0, zp1, dp, z);
  hipLaunchKernelGGL(k_gemm2, dim3(288, 4), dim3(256), 0, stream, z, vwb, v_b, x, out);
}

// Round 4
// 284.059 us; speedup vs baseline: 1.3397x; 1.0547x over previous
//
#include <hip/hip_runtime.h>

// ---------------------------------------------------------------------------
// SOABlock: f,g = BN(ReLU(1x1conv)), h = 1x1conv, attn = softmax(f^T g /16),
// z = attn @ h^T, out = v(z) + x.   B=16, C=512, MID=256, N=48*48=2304.
// ---------------------------------------------------------------------------

#define B_    16
#define C_    512
#define MID_  256
#define N_    2304
#define NT_   (B_ * N_)          // 36864

typedef unsigned short u16;
typedef unsigned int   u32;
typedef unsigned long long ull;
typedef short s16x8 __attribute__((ext_vector_type(8)));   // 8 bf16 (4 VGPR)
typedef float f32x4 __attribute__((ext_vector_type(4)));
typedef float f32x16 __attribute__((ext_vector_type(16)));

// exp constants: P = exp(S/16 - 20) = exp2(S*K1F - K2F)
#define K1F 0.09016844005556021f
#define K2F 28.853900817779268f

#define MFMA16(a, b, c) __builtin_amdgcn_mfma_f32_16x16x32_bf16(a, b, c, 0, 0, 0)
#define MFMA32(a, b, c) __builtin_amdgcn_mfma_f32_32x32x16_bf16(a, b, c, 0, 0, 0)

__device__ __forceinline__ u16 f2bf(float f) {
  unsigned int u = __float_as_uint(f);
  return (u16)((u + 0x7FFFu + ((u >> 16) & 1u)) >> 16);
}
__device__ __forceinline__ u32 pack2bf(float a, float b) {
  return (u32)f2bf(a) | ((u32)f2bf(b) << 16);
}
__device__ __forceinline__ ull pack4bf(float a, float b, float c, float d) {
  return (ull)pack2bf(a, b) | ((ull)pack2bf(c, d) << 32);
}
// truncating pack (P values; ~0.2% bias is fine, saves VALU)
__device__ __forceinline__ u32 pack2t(float a, float b) {
  return (__float_as_uint(a) >> 16) | (__float_as_uint(b) & 0xffff0000u);
}
__device__ __forceinline__ float bf2f(u32 v) { return __uint_as_float(v << 16); }

#define GLL16(src, dst)                                                        \
  __builtin_amdgcn_global_load_lds(                                            \
      (const __attribute__((address_space(1))) void*)(src),                    \
      (__attribute__((address_space(3))) void*)(dst), 16, 0, 0)

// ---------------------------------------------------------------------------
// ws layout (bytes)
#define OFF_XT   0ull            // xT bf16 [36864][512]; later zp splits 0,1
#define OFF_FG   37748736ull     // fg bf16 [36864][512]; later combined z bf16
#define OFF_HT   75497472ull     // hT bf16 [16][256][2304]
#define OFF_WB   94371840ull     // Wfgh bf16 [768][512]
#define OFF_VW   95158272ull     // v_w bf16 [512][256]
#define OFF_BIAS 95420416ull     // bias f32 [768]
#define ZP_ELEMS (9437184ull)    // 36864*256 per split

// ---------------------------------------------------------------------------
// K0: fold BN into conv weights, convert weights to bf16.
__global__ __launch_bounds__(64) void k_prep(
    const float* __restrict__ f_w, const float* __restrict__ f_b2, const float* __restrict__ f_gamma,
    const float* __restrict__ f_beta, const float* __restrict__ f_mean, const float* __restrict__ f_var,
    const float* __restrict__ g_w, const float* __restrict__ g_b2, const float* __restrict__ g_gamma,
    const float* __restrict__ g_beta, const float* __restrict__ g_mean, const float* __restrict__ g_var,
    const float* __restrict__ h_w, const float* __restrict__ h_b2, const float* __restrict__ v_w,
    u16* __restrict__ Wb, u16* __restrict__ vwb, float* __restrict__ biasb)
{
  const int bid = blockIdx.x, t = threadIdx.x;
  if (bid < 768) {
    const int o = bid;
    const float* wsrc;
    float scale, bias_v;
    if (o < 256) {
      scale = f_gamma[o] * rsqrtf(f_var[o] + 1e-5f);
      wsrc = f_w + o * 512;
      bias_v = (f_b2[o] - f_mean[o]) * scale + f_beta[o];
    } else if (o < 512) {
      const int i = o - 256;
      scale = g_gamma[i] * rsqrtf(g_var[i] + 1e-5f);
      wsrc = g_w + i * 512;
      bias_v = (g_b2[i] - g_mean[i]) * scale + g_beta[i];
    } else {
      const int i = o - 512;
      scale = 1.0f;
      wsrc = h_w + i * 512;
      bias_v = h_b2[i];
    }
#pragma unroll
    for (int j = 0; j < 8; ++j)
      Wb[o * 512 + t * 8 + j] = f2bf(wsrc[t * 8 + j] * scale);
    if (t == 0) biasb[o] = bias_v;
  } else {
    const int r = bid - 768;
#pragma unroll
    for (int j = 0; j < 4; ++j)
      vwb[r * 256 + t * 4 + j] = f2bf(v_w[r * 256 + t * 4 + j]);
  }
}

// ---------------------------------------------------------------------------
// K1: x [b][c][n] f32  ->  xT [b*n][c] bf16   (64x64 tiles via LDS)
__global__ __launch_bounds__(256) void k_trx(const float* __restrict__ x, u16* __restrict__ xT)
{
  __shared__ __align__(16) u16 T[64 * 72];
  const int t = threadIdx.x;
  const int n0 = blockIdx.x * 64, c0 = blockIdx.y * 64, b = blockIdx.z;
#pragma unroll
  for (int it = 0; it < 4; ++it) {
    const int cr = it * 16 + (t >> 4);
    const int nc = (t & 15) * 4;
    const float4 v = *(const float4*)(x + ((size_t)(b * 512 + c0 + cr)) * N_ + n0 + nc);
    T[cr * 72 + nc + 0] = f2bf(v.x);
    T[cr * 72 + nc + 1] = f2bf(v.y);
    T[cr * 72 + nc + 2] = f2bf(v.z);
    T[cr * 72 + nc + 3] = f2bf(v.w);
  }
  __syncthreads();
#pragma unroll
  for (int it = 0; it < 2; ++it) {
    const int nr = it * 32 + (t >> 3);
    const int ch = t & 7;
    s16x8 val;
#pragma unroll
    for (int j = 0; j < 8; ++j) val[j] = (short)T[(ch * 8 + j) * 72 + nr];
    *(s16x8*)(xT + ((size_t)(b * N_ + n0 + nr)) * 512 + c0 + ch * 8) = val;
  }
}

// ---------------------------------------------------------------------------
// K2: GEMM1  D[o][n] = Wfgh[o][c] * x[c][n]  (+bias, relu for o<512)
__global__ __launch_bounds__(256) void k_gemm1(const u16* __restrict__ Wb, const u16* __restrict__ xT,
                                               const float* __restrict__ biasb,
                                               u16* __restrict__ fg, u16* __restrict__ hT)
{
  __shared__ __align__(16) u16 Al[128 * 64];
  __shared__ __align__(16) u16 Bl[128 * 64];
  const int tid = threadIdx.x, lane = tid & 63, w = tid >> 6;
  const int wr = w >> 1, wc = w & 1;
  const int row16 = lane & 15, g = lane >> 4;
  const int nt = blockIdx.x, mt = blockIdx.y;
  const int nbase = nt * 128;
  const int sr = lane >> 3, sj = lane & 7;

  f32x4 acc[4][4] = {};

  for (int kt = 0; kt < 8; ++kt) {
#pragma unroll
    for (int s = 0; s < 4; ++s) {
      const int r = s * 32 + w * 8 + sr;
      GLL16(Wb + (size_t)(mt * 128 + r) * 512 + kt * 64 + ((sj ^ (r & 7)) * 8), Al + (s * 32 + w * 8) * 64);
    }
#pragma unroll
    for (int s = 0; s < 4; ++s) {
      const int r = s * 32 + w * 8 + sr;
      GLL16(xT + (size_t)(nbase + r) * 512 + kt * 64 + ((sj ^ (r & 7)) * 8), Bl + (s * 32 + w * 8) * 64);
    }
    __syncthreads();
#pragma unroll
    for (int kk = 0; kk < 2; ++kk) {
      s16x8 a[4], b[4];
#pragma unroll
      for (int m = 0; m < 4; ++m) {
        const int row = wr * 64 + m * 16 + row16;
        a[m] = *(const s16x8*)(Al + row * 64 + (((kk * 4 + g) ^ (row & 7)) * 8));
      }
#pragma unroll
      for (int n = 0; n < 4; ++n) {
        const int row = wc * 64 + n * 16 + row16;
        b[n] = *(const s16x8*)(Bl + row * 64 + (((kk * 4 + g) ^ (row & 7)) * 8));
      }
#pragma unroll
      for (int m = 0; m < 4; ++m)
#pragma unroll
        for (int n = 0; n < 4; ++n)
          acc[m][n] = MFMA16(a[m], b[n], acc[m][n]);
    }
    __syncthreads();
  }

  const int bt = nbase / N_;
  if (mt < 4) {
#pragma unroll
    for (int m = 0; m < 4; ++m) {
      const int o0 = mt * 128 + wr * 64 + m * 16 + g * 4;
      const float b0 = biasb[o0], b1 = biasb[o0 + 1], b2 = biasb[o0 + 2], b3 = biasb[o0 + 3];
#pragma unroll
      for (int n = 0; n < 4; ++n) {
        const int nn = nbase + wc * 64 + n * 16 + row16;
        const f32x4 v = acc[m][n];
        *(ull*)(fg + (size_t)nn * 512 + o0) =
            pack4bf(fmaxf(v[0] + b0, 0.f), fmaxf(v[1] + b1, 0.f),
                    fmaxf(v[2] + b2, 0.f), fmaxf(v[3] + b3, 0.f));
      }
    }
  } else {
#pragma unroll
    for (int m = 0; m < 4; ++m) {
      const int o0 = mt * 128 + wr * 64 + m * 16 + g * 4;
#pragma unroll
      for (int n = 0; n < 4; ++n) {
        const int nn = nbase + wc * 64 + n * 16 + row16;
        const int nl = nn - bt * N_;
#pragma unroll
        for (int i = 0; i < 4; ++i)
          hT[(size_t)(bt * 256 + (o0 - 512) + i) * N_ + nl] = f2bf(acc[m][n][i] + biasb[o0 + i]);
      }
    }
  }
}

// ---------------------------------------------------------------------------
// K3: flash attention v4 — flash3 inner loop, KV split 4-way for tail packing.
//   128 q/block, 4 waves x 32 q each; KV tile 32, K/V double-buffered in LDS,
//   ONE barrier per iteration.  S^T = mfma32(K, Q): lane holds P[kv-quads][q];
//   PV B-frag built in-register with packs + shfl_xor(32).  1152 blocks
//   (16 b x 18 q x 4 sp) with XCD-locality swizzle (2 batches per XCD, sp
//   outer within batch so concurrent blocks share the K/V range in L2).
__global__ __launch_bounds__(256, 2) void k_flash4(const u16* __restrict__ fg, const u16* __restrict__ hT,
                                                   u16* __restrict__ zp0, u16* __restrict__ zp1,
                                                   u16* __restrict__ zp2, u16* __restrict__ zp3,
                                                   float* __restrict__ dp)
{
  __shared__ __align__(16) u16 Sh[32768];   // 64KB: K[2]@0,8192  V[2]@16384,24576
  const int tid = threadIdx.x, lane = tid & 63, w = tid >> 6;
  const int q5 = lane & 31, hi = lane >> 5;

  // XCD-locality block swizzle: 1152 blocks; xcd = L&7 handles batches {2x,2x+1}
  const int L = blockIdx.x;
  const int xcd = L & 7, s = L >> 3;          // s 0..143
  const int b = xcd * 2 + (s >= 72 ? 1 : 0);
  const int j = (s >= 72) ? s - 72 : s;       // 0..71
  const int qb = (j % 18) * 128;
  const int sp = j / 18;                      // KV split id 0..3
  const int t0 = sp * 18;                     // first kv tile

  // Q fragments (B-operand): lane(q5,hi) holds Q[qrow][ks*16 + hi*8 .. +7]
  const int qrow = b * N_ + qb + w * 32 + q5;
  s16x8 qf[16];
#pragma unroll
  for (int ks = 0; ks < 16; ++ks)
    qf[ks] = *(const s16x8*)(fg + (size_t)qrow * 512 + ks * 16 + hi * 8);

  f32x16 accz[8] = {};     // z^T[c = ct*32 + rowpat][q = q5]
  float dsum = 0.f;

  // ---- staging helpers ----
  auto stageK = [&](int m0, int buf) {
    u16* dst = Sh + buf * 8192;
#pragma unroll
    for (int s2 = 0; s2 < 4; ++s2) {
      const int i = w * 4 + s2;
      const int r = 2 * i + hi;
      const int chp = lane & 31;
      const int ch = (chp & 24) | ((chp ^ (r & 7)) & 7);
      GLL16(fg + (size_t)(b * N_ + m0 + r) * 512 + 256 + ch * 8, dst + i * 512);
    }
  };
  auto stageV = [&](int m0, int buf) {
    u16* dst = Sh + 16384 + buf * 8192;
#pragma unroll
    for (int s2 = 0; s2 < 4; ++s2) {
      const int i = w * 4 + s2;
      const int r2 = i * 8 + (lane >> 3);
      const int ch = (lane & 7) ^ (r2 & 7);
      const int c = 2 * r2 + (ch >> 2);
      GLL16(hT + (size_t)(b * 256 + c) * N_ + m0 + (ch & 3) * 8, dst + i * 512);
    }
  };

  stageK(t0 * 32, 0);
  stageV(t0 * 32, 0);

  for (int it = 0; it < 18; ++it) {
    const int cur = it & 1;
    __syncthreads();                 // tile[cur] staged; prev readers of [cur^1] done
    if (it + 1 < 18) {               // prefetch next tile: full iteration to land
      stageK((t0 + it + 1) * 32, cur ^ 1);
      stageV((t0 + it + 1) * 32, cur ^ 1);
    }

    // ---- S^T[kv][q] = K * Q  (one 32x32 tile, K=256 in 16 steps)
    const u16* KL = Sh + cur * 8192;
    const int kvb = q5 * 256;        // A-row = kv = lane&31
    f32x16 sT = {};
    __builtin_amdgcn_s_setprio(1);
#pragma unroll
    for (int ks = 0; ks < 16; ++ks) {
      const int ch = ks * 2 + hi;
      const int chp = (ch & 24) | ((ch ^ (q5 & 7)) & 7);
      const s16x8 kf = *(const s16x8*)(KL + kvb + chp * 8);
      sT = MFMA32(kf, qf[ks], sT);
    }
    __builtin_amdgcn_s_setprio(0);

    // ---- exp + in-register P packs;  own quads O[2m+j], partner X via shfl
    u32 O[8], X[8];
    float lsum = 0.f;
#pragma unroll
    for (int m = 0; m < 4; ++m) {
      const float p0 = exp2f(sT[4 * m + 0] * K1F - K2F);
      const float p1 = exp2f(sT[4 * m + 1] * K1F - K2F);
      const float p2 = exp2f(sT[4 * m + 2] * K1F - K2F);
      const float p3 = exp2f(sT[4 * m + 3] * K1F - K2F);
      lsum += (p0 + p1) + (p2 + p3);
      O[2 * m] = pack2t(p0, p1);
      O[2 * m + 1] = pack2t(p2, p3);
    }
    dsum += lsum;
#pragma unroll
    for (int r = 0; r < 8; ++r) X[r] = (u32)__shfl_xor((int)O[r], 32);

    s16x8 pf[2];
#pragma unroll
    for (int h = 0; h < 2; ++h) {
      union { u32 wd[4]; s16x8 v; } u;
      u.wd[0] = hi ? X[4 * h + 2] : O[4 * h + 0];
      u.wd[1] = hi ? X[4 * h + 3] : O[4 * h + 1];
      u.wd[2] = hi ? O[4 * h + 2] : X[4 * h + 0];
      u.wd[3] = hi ? O[4 * h + 3] : X[4 * h + 1];
      pf[h] = u.v;
    }

    // ---- PV: accz[ct] += V^T(c-rows) * P   (8 c-tiles x 2 k-halves)
    const u16* VL = Sh + 16384 + cur * 8192;
    __builtin_amdgcn_s_setprio(1);
#pragma unroll
    for (int h = 0; h < 2; ++h)
#pragma unroll
      for (int ct = 0; ct < 8; ++ct) {
        const int c = ct * 32 + q5;
        const int r2 = c >> 1;
        const int ch = (c & 1) * 4 + h * 2 + hi;
        const int chp = ch ^ (r2 & 7);
        const s16x8 vf = *(const s16x8*)(VL + r2 * 64 + chp * 8);
        accz[ct] = MFMA32(vf, pf[h], accz[ct]);
      }
    __builtin_amdgcn_s_setprio(0);
  }

  // ---- denominator: combine hi-halves; lane q (hi=0) stores
  const float dtot = dsum + (float)__shfl_xor(dsum, 32);
  if (hi == 0)
    dp[(size_t)sp * NT_ + b * N_ + qb + w * 32 + q5] = dtot;

  // ---- transpose z^T -> [n][c] via per-wave LDS region, coalesced store
  __syncthreads();                   // everyone done with K/V LDS
  u16* R = Sh + w * 8192;            // 16KB per wave: [32 n][256 c], quad-swz
#pragma unroll
  for (int ct = 0; ct < 8; ++ct)
#pragma unroll
    for (int m = 0; m < 4; ++m) {
      const int quad = ct * 8 + 2 * m + hi;       // c-quad index (c = quad*4..)
      const int pos = quad ^ (q5 & 7);
      *(ull*)(R + q5 * 256 + pos * 4) =
          pack4bf(accz[ct][4 * m + 0], accz[ct][4 * m + 1],
                  accz[ct][4 * m + 2], accz[ct][4 * m + 3]);
    }
  u16* zp = (sp < 2) ? (sp ? zp1 : zp0) : (sp == 2 ? zp2 : zp3);
  const size_t gbase = (size_t)(b * N_ + qb + w * 32) * 256;
#pragma unroll
  for (int n = 0; n < 32; ++n) {
    const ull v = *(const ull*)(R + n * 256 + ((lane ^ (n & 7)) & 63) * 4);
    *(ull*)(zp + gbase + n * 256 + lane * 4) = v;
  }
}

// ---------------------------------------------------------------------------
// K3b: combine partials:  z[n][c] = (sum_s zp_s[n][c]) / (sum_s dp_s[n])
__global__ __launch_bounds__(256) void k_combine(const u16* __restrict__ zp0, const u16* __restrict__ zp1,
                                                 const u16* __restrict__ zp2, const u16* __restrict__ zp3,
                                                 const float* __restrict__ dp, u16* __restrict__ zout)
{
  const int gid = blockIdx.x * 256 + threadIdx.x;
  const int n = gid >> 6;
  const int c = (gid & 63) * 4;
  const float inv = 1.0f / (dp[n] + dp[NT_ + n] + dp[2 * NT_ + n] + dp[3 * NT_ + n]);
  const ull va = *(const ull*)(zp0 + (size_t)n * 256 + c);
  const ull vb = *(const ull*)(zp1 + (size_t)n * 256 + c);
  const ull vc = *(const ull*)(zp2 + (size_t)n * 256 + c);
  const ull vd = *(const ull*)(zp3 + (size_t)n * 256 + c);
  const float a0 = bf2f((u32)(va & 0xffff)) + bf2f((u32)(vb & 0xffff)) +
                   bf2f((u32)(vc & 0xffff)) + bf2f((u32)(vd & 0xffff));
  const float a1 = bf2f((u32)((va >> 16) & 0xffff)) + bf2f((u32)((vb >> 16) & 0xffff)) +
                   bf2f((u32)((vc >> 16) & 0xffff)) + bf2f((u32)((vd >> 16) & 0xffff));
  const float a2 = bf2f((u32)((va >> 32) & 0xffff)) + bf2f((u32)((vb >> 32) & 0xffff)) +
                   bf2f((u32)((vc >> 32) & 0xffff)) + bf2f((u32)((vd >> 32) & 0xffff));
  const float a3 = bf2f((u32)(va >> 48)) + bf2f((u32)(vb >> 48)) +
                   bf2f((u32)(vc >> 48)) + bf2f((u32)(vd >> 48));
  *(ull*)(zout + (size_t)n * 256 + c) = pack4bf(a0 * inv, a1 * inv, a2 * inv, a3 * inv);
}

// ---------------------------------------------------------------------------
// K4: GEMM2  out[b][o][n] = v_w[o][c] * z[c][n] + v_b[o] + x[b][o][n]
__global__ __launch_bounds__(256) void k_gemm2(const u16* __restrict__ zb, const u16* __restrict__ vwb,
                                               const float* __restrict__ v_b, const float* __restrict__ x,
                                               float* __restrict__ out)
{
  __shared__ __align__(16) u16 Al[128 * 64];
  __shared__ __align__(16) u16 Bl[128 * 64];
  const int tid = threadIdx.x, lane = tid & 63, w = tid >> 6;
  const int wr = w >> 1, wc = w & 1;
  const int row16 = lane & 15, g = lane >> 4;
  const int nt = blockIdx.x, ot = blockIdx.y;
  const int nbase = nt * 128;
  const int sr = lane >> 3, sj = lane & 7;

  f32x4 acc[4][4] = {};

  for (int kt = 0; kt < 4; ++kt) {
#pragma unroll
    for (int s = 0; s < 4; ++s) {
      const int r = s * 32 + w * 8 + sr;
      GLL16(zb + (size_t)(nbase + r) * 256 + kt * 64 + ((sj ^ (r & 7)) * 8), Al + (s * 32 + w * 8) * 64);
    }
#pragma unroll
    for (int s = 0; s < 4; ++s) {
      const int r = s * 32 + w * 8 + sr;
      GLL16(vwb + (size_t)(ot * 128 + r) * 256 + kt * 64 + ((sj ^ (r & 7)) * 8), Bl + (s * 32 + w * 8) * 64);
    }
    __syncthreads();
#pragma unroll
    for (int kk = 0; kk < 2; ++kk) {
      s16x8 a[4], b[4];
#pragma unroll
      for (int m = 0; m < 4; ++m) {
        const int row = wr * 64 + m * 16 + row16;
        a[m] = *(const s16x8*)(Al + row * 64 + (((kk * 4 + g) ^ (row & 7)) * 8));
      }
#pragma unroll
      for (int n = 0; n < 4; ++n) {
        const int row = wc * 64 + n * 16 + row16;
        b[n] = *(const s16x8*)(Bl + row * 64 + (((kk * 4 + g) ^ (row & 7)) * 8));
      }
#pragma unroll
      for (int m = 0; m < 4; ++m)
#pragma unroll
        for (int n = 0; n < 4; ++n)
          acc[m][n] = MFMA16(a[m], b[n], acc[m][n]);
    }
    __syncthreads();
  }

  const int bt = nbase / N_;
#pragma unroll
  for (int m = 0; m < 4; ++m) {
    const int nl0 = (nbase - bt * N_) + wr * 64 + m * 16 + g * 4;
#pragma unroll
    for (int n = 0; n < 4; ++n) {
      const int o = ot * 128 + wc * 64 + n * 16 + row16;
      const float vb = v_b[o];
      const size_t off = (size_t)(bt * 512 + o) * N_ + nl0;
      const float4 xv = *(const float4*)(x + off);
      float4 r;
      r.x = acc[m][n][0] + vb + xv.x;
      r.y = acc[m][n][1] + vb + xv.y;
      r.z = acc[m][n][2] + vb + xv.z;
      r.w = acc[m][n][3] + vb + xv.w;
      *(float4*)(out + off) = r;
    }
  }
}

// ---------------------------------------------------------------------------
extern "C" void kernel_launch(void* const* d_in, const int* in_sizes, int n_in,
                              void* d_out, int out_size, void* d_ws, size_t ws_size,
                              hipStream_t stream)
{
  const float* x       = (const float*)d_in[0];
  const float* f_w     = (const float*)d_in[1];
  const float* f_b     = (const float*)d_in[2];
  const float* f_gamma = (const float*)d_in[3];
  const float* f_beta  = (const float*)d_in[4];
  const float* f_mean  = (const float*)d_in[5];
  const float* f_var   = (const float*)d_in[6];
  const float* g_w     = (const float*)d_in[7];
  const float* g_b     = (const float*)d_in[8];
  const float* g_gamma = (const float*)d_in[9];
  const float* g_beta  = (const float*)d_in[10];
  const float* g_mean  = (const float*)d_in[11];
  const float* g_var   = (const float*)d_in[12];
  const float* h_w     = (const float*)d_in[13];
  const float* h_b     = (const float*)d_in[14];
  const float* v_w     = (const float*)d_in[15];
  const float* v_b     = (const float*)d_in[16];

  char* ws = (char*)d_ws;
  u16*  xT    = (u16*)(ws + OFF_XT);
  u16*  fg    = (u16*)(ws + OFF_FG);
  u16*  hT    = (u16*)(ws + OFF_HT);
  u16*  Wb    = (u16*)(ws + OFF_WB);
  u16*  vwb   = (u16*)(ws + OFF_VW);
  float* biasb = (float*)(ws + OFF_BIAS);
  float* out  = (float*)d_out;

  // flash partials: splits 0,1 over the dead xT region; splits 2,3 and the
  // denominators in d_out (fully overwritten by k_gemm2 afterwards).
  u16*  zp0 = (u16*)(ws + OFF_XT);
  u16*  zp1 = (u16*)(ws + OFF_XT + 2 * ZP_ELEMS);       // byte offset = 2B*elems
  u16*  zp2 = (u16*)d_out;
  u16*  zp3 = (u16*)d_out + ZP_ELEMS;
  float* dp = (float*)((char*)d_out + 4 * ZP_ELEMS);    // 4*NT_ floats
  u16*  z   = (u16*)(ws + OFF_FG);   // combined z overwrites dead fg region

  hipLaunchKernelGGL(k_prep, dim3(1280), dim3(64), 0, stream,
                     f_w, f_b, f_gamma, f_beta, f_mean, f_var,
                     g_w, g_b, g_gamma, g_beta, g_mean, g_var,
                     h_w, h_b, v_w, Wb, vwb, biasb);
  hipLaunchKernelGGL(k_trx, dim3(36, 8, 16), dim3(256), 0, stream, x, xT);
  hipLaunchKernelGGL(k_gemm1, dim3(288, 6), dim3(256), 0, stream, Wb, xT, biasb, fg, hT);
  hipLaunchKernelGGL(k_flash4, dim3(1152), dim3(256), 0, stream, fg, hT, zp0, zp1, zp2, zp3, dp);
  hipLaunchKernelGGL(k_combine, dim3(9216), dim3(256), 0, stream, zp0, zp1, zp2, zp3, dp, z);
  hipLaunchKernelGGL(k_gemm2, dim3(288, 4), dim3(256), 0, stream, z, vwb, v_b, x, out);
}